// Round 9
// baseline (1315.819 us; speedup 1.0000x reference)
//
#include <hip/hip_runtime.h>

typedef __attribute__((ext_vector_type(8))) short short8;
typedef __attribute__((ext_vector_type(4))) float f32x4;

#define NEGV -10000.0f

__device__ __forceinline__ float bfu2f(unsigned short u) {
  unsigned int x = ((unsigned int)u) << 16;
  return __builtin_bit_cast(float, x);
}
__device__ __forceinline__ unsigned short f2bfu(float f) {
  unsigned int x = __builtin_bit_cast(unsigned int, f);
  x += 0x7fffu + ((x >> 16) & 1u);
  return (unsigned short)(x >> 16);
}
__device__ __forceinline__ float fsig(float x) {
  return 1.0f / (1.0f + __expf(-x));
}
__device__ __forceinline__ float ftanh(float x) {
  x = fminf(15.0f, fmaxf(-15.0f, x));
  float e = __expf(-2.0f * x);
  return (1.0f - e) / (1.0f + e);
}

// ---------------- prep: convert weights to bf16, build combined bias ----------------
__global__ __launch_bounds__(256) void prep_kernel(
    const float* __restrict__ wihf, const float* __restrict__ wihb,
    const float* __restrict__ whhf, const float* __restrict__ whhb,
    const float* __restrict__ wo, const float* __restrict__ bfv,
    const float* __restrict__ bbv,
    unsigned short* __restrict__ wih_c, unsigned short* __restrict__ whh_c,
    unsigned short* __restrict__ wout_c, float* __restrict__ bias_c) {
  size_t i = (size_t)blockIdx.x * 256 + threadIdx.x;
  const size_t n_half = 2048u * 512u;
  const size_t n_wih = 2u * n_half;
  const size_t n_wo = 24u * 1024u;
  if (i < n_wih) {
    float v = (i < n_half) ? wihf[i] : wihb[i - n_half];
    wih_c[i] = f2bfu(v);
  } else if (i < 2u * n_wih) {
    size_t j = i - n_wih;
    float v = (j < n_half) ? whhf[j] : whhb[j - n_half];
    whh_c[j] = f2bfu(v);
  } else if (i < 2u * n_wih + n_wo) {
    size_t j = i - 2u * n_wih;
    wout_c[j] = f2bfu(wo[j]);
  } else if (i < 2u * n_wih + n_wo + 4096u) {
    size_t j = i - 2u * n_wih - n_wo;
    bias_c[j] = (j < 2048u) ? bfv[j] : bbv[j - 2048u];
  }
}

// ---------------- GEMM with fused gather:
// xg[16384][4096] = bf16(emb[xw[m]])[512] @ wih_c[4096][512]^T + bias ----
__global__ __launch_bounds__(256) void gemm_xg_kernel(
    const int* __restrict__ xw,             // [16384]
    const float* __restrict__ emb,          // [50000][512] f32
    const unsigned short* __restrict__ Bm,  // [4096][512] bf16
    const float* __restrict__ bias,         // [4096]
    unsigned short* __restrict__ C) {       // [16384][4096] bf16
  __shared__ alignas(16) char As[16384];
  __shared__ alignas(16) char Bs[16384];
  int m0 = blockIdx.x * 128, n0 = blockIdx.y * 128;
  int tid = threadIdx.x;
  int wv = tid >> 6, l = tid & 63;
  int wm = wv >> 1, wn = wv & 1;
  int col = l & 15, quad = l >> 4;
  // hoist token indices: each thread stages rows {q*32 + (tid>>3)} for q=0..3
  int tok[4];
#pragma unroll
  for (int q = 0; q < 4; ++q) tok[q] = xw[m0 + ((q * 4096 + tid * 16) >> 7)];
  f32x4 zero4 = {0.f, 0.f, 0.f, 0.f};
  f32x4 acc[4][4];
#pragma unroll
  for (int i = 0; i < 4; ++i)
#pragma unroll
    for (int j = 0; j < 4; ++j) acc[i][j] = zero4;
  for (int kt = 0; kt < 8; ++kt) {
#pragma unroll
    for (int q = 0; q < 4; ++q) {
      int o = q * 4096 + tid * 16;
      int row = o >> 7;
      int cb = o & 127;
      int swz = cb ^ ((row & 7) << 4);
      // A: gather row from f32 embedding, convert to bf16 in-register
      const float* sa = emb + (size_t)tok[q] * 512 + kt * 64 + (cb >> 1);
      f32x4 f0 = *(const f32x4*)sa;
      f32x4 f1 = *(const f32x4*)(sa + 4);
      short8 va;
#pragma unroll
      for (int j = 0; j < 4; ++j) {
        va[j] = (short)f2bfu(f0[j]);
        va[4 + j] = (short)f2bfu(f1[j]);
      }
      *(short8*)(As + row * 128 + swz) = va;
      short8 vb = *(const short8*)(Bm + (size_t)(n0 + row) * 512 + kt * 64 + (cb >> 1));
      *(short8*)(Bs + row * 128 + swz) = vb;
    }
    __syncthreads();
#pragma unroll
    for (int kk = 0; kk < 2; ++kk) {
      short8 af[4], bf8[4];
#pragma unroll
      for (int mi = 0; mi < 4; ++mi) {
        int r = wm * 64 + mi * 16 + col;
        int cb = kk * 64 + quad * 16;
        af[mi] = *(const short8*)(As + r * 128 + (cb ^ ((r & 7) << 4)));
      }
#pragma unroll
      for (int ni = 0; ni < 4; ++ni) {
        int r = wn * 64 + ni * 16 + col;
        int cb = kk * 64 + quad * 16;
        bf8[ni] = *(const short8*)(Bs + r * 128 + (cb ^ ((r & 7) << 4)));
      }
#pragma unroll
      for (int mi = 0; mi < 4; ++mi)
#pragma unroll
        for (int ni = 0; ni < 4; ++ni)
          acc[mi][ni] = __builtin_amdgcn_mfma_f32_16x16x32_bf16(af[mi], bf8[ni], acc[mi][ni], 0, 0, 0);
    }
    __syncthreads();
  }
#pragma unroll
  for (int ni = 0; ni < 4; ++ni) {
    int cg = n0 + wn * 64 + ni * 16 + col;
    float bv = bias[cg];
#pragma unroll
    for (int mi = 0; mi < 4; ++mi) {
#pragma unroll
      for (int r = 0; r < 4; ++r) {
        int rg = m0 + wm * 64 + mi * 16 + quad * 4 + r;
        C[(size_t)rg * 4096 + cg] = f2bfu(acc[mi][ni][r] + bv);
      }
    }
  }
}

// ---------------- persistent LSTM scan: wave-decoupled, poll-on-data (PROVEN protocol) ----------------
// 512 wgs x 64 threads. Wave wid: dir=wid&1, g=(wid>>1)&63, wv=(wid>>7)&3.
// ALL h traffic sc0 sc1 (IF$-coherent, single copy, no L2 aliasing). h planes
// pre-poisoned 0xFFFF (bf16 NaN, unreachable: |h|<1); the data IS the flag:
// producers store 16B chunks (single atomic-at-IF$ store each, no drain/flag);
// readers re-issue their 16 h-loads until no chunk starts with the sentinel.
// Poll safety invariant (R7 lesson): issue 16 loads -> vmcnt(0) ->
// sched_barrier -> check; asm-loaded registers are NEVER live while their
// loads are in flight (no partial vmcnt, no speculative sets).
// Safe additions (R6-proven): xg ping-pong asm prefetch one step ahead,
// even/odd MFMA accumulator split, s_setprio around compute.
__global__ __launch_bounds__(64, 1) void scan_kernel(
    const unsigned short* __restrict__ whh,  // [2][2048][512] bf16
    const unsigned short* __restrict__ xg,   // [16384][4096] bf16
    unsigned short* __restrict__ hfp,
    unsigned short* __restrict__ hbp) {
  __shared__ alignas(16) unsigned short tbuf[128];  // 256B transpose scratch
  int wid = blockIdx.x;
  int l = threadIdx.x;
  int dir = wid & 1;
  int g = (wid >> 1) & 63;
  int wv = (wid >> 7) & 3;
  int u0 = g * 8;
  int col = l & 15, quad = l >> 4;
  int b_row = wv * 16 + quad * 4;
  // asm-resident w_hh fragments: 2 gate-pairs x 16 K-chunks
  short8 bfr[2][16];
#pragma unroll
  for (int n = 0; n < 2; ++n) {
    int blk = n * 2 + (col >> 3);  // 0..3 = i,f,g,o
    int gr = blk * 512 + u0 + (col & 7);
    const char* base = (const char*)(whh + ((size_t)dir * 2048 + gr) * 512 + quad * 8);
#pragma unroll
    for (int kk = 0; kk < 16; ++kk)
      asm volatile("global_load_dwordx4 %0, %1, off" : "=v"(bfr[n][kk]) : "v"(base + kk * 64));
  }
  unsigned short* hseq = dir ? hbp : hfp;
  int gc0 = dir * 2048 + (col >> 3) * 512 + u0 + (col & 7);  // i/f gate col; +1024 elems = g/o
  float cst[4] = {0.f, 0.f, 0.f, 0.f};
  f32x4 zero4 = {0.f, 0.f, 0.f, 0.f};
  short8 af[16];
  unsigned int xA[8], xB[8];
  {  // prologue: xg for s=0
    int t0 = dir ? 255 : 0;
#pragma unroll
    for (int r = 0; r < 4; ++r) {
      const char* xa = (const char*)(xg + ((size_t)t0 * 64 + b_row + r) * 4096 + gc0);
      asm volatile("global_load_ushort %0, %1, off" : "=v"(xA[r]) : "v"(xa));
      asm volatile("global_load_ushort %0, %1, off" : "=v"(xA[4 + r]) : "v"(xa + 2048));
    }
  }
  asm volatile("s_waitcnt vmcnt(0)" ::: "memory");
  __builtin_amdgcn_sched_barrier(0);

#define SCAN_STEP(S_, XU_, XP_)                                                             \
  {                                                                                         \
    int s_ = (S_);                                                                          \
    int t_ = dir ? (255 - s_) : s_;                                                         \
    f32x4 ae0 = zero4, ao0 = zero4, ae1 = zero4, ao1 = zero4;                               \
    if (s_ > 0) {                                                                           \
      int tprev = t_ + (dir ? 1 : -1);                                                      \
      const char* pbase = (const char*)hseq + (size_t)tprev * 65536 + quad * 1024 +         \
                          (wv * 16 + col) * 16;                                             \
      unsigned long long bal;                                                               \
      do {                                                                                  \
        _Pragma("unroll") for (int kk = 0; kk < 16; ++kk)                                   \
            asm volatile("global_load_dwordx4 %0, %1, off sc0 sc1"                          \
                         : "=v"(af[kk]) : "v"(pbase + kk * 4096));                          \
        asm volatile("s_waitcnt vmcnt(0)" ::: "memory");                                    \
        __builtin_amdgcn_sched_barrier(0);                                                  \
        unsigned int st_ = 0u;                                                              \
        _Pragma("unroll") for (int kk = 0; kk < 16; ++kk)                                   \
            st_ |= (((unsigned short)af[kk][0]) == 0xFFFFu) ? 1u : 0u;                      \
        bal = __ballot(st_ != 0u);                                                          \
      } while (bal != 0ull);                                                                \
      __builtin_amdgcn_s_setprio(1);                                                        \
      __builtin_amdgcn_sched_barrier(0);                                                    \
      _Pragma("unroll") for (int kk = 0; kk < 8; ++kk) {                                    \
        ae0 = __builtin_amdgcn_mfma_f32_16x16x32_bf16(af[2 * kk], bfr[0][2 * kk], ae0, 0,   \
                                                      0, 0);                                \
        ae1 = __builtin_amdgcn_mfma_f32_16x16x32_bf16(af[2 * kk], bfr[1][2 * kk], ae1, 0,   \
                                                      0, 0);                                \
        ao0 = __builtin_amdgcn_mfma_f32_16x16x32_bf16(af[2 * kk + 1], bfr[0][2 * kk + 1],   \
                                                      ao0, 0, 0, 0);                        \
        ao1 = __builtin_amdgcn_mfma_f32_16x16x32_bf16(af[2 * kk + 1], bfr[1][2 * kk + 1],   \
                                                      ao1, 0, 0, 0);                        \
      }                                                                                     \
    }                                                                                       \
    {                                                                                       \
      int sn = (s_ < 255) ? (s_ + 1) : 255;                                                 \
      int tn = dir ? (255 - sn) : sn;                                                       \
      _Pragma("unroll") for (int r = 0; r < 4; ++r) {                                       \
        const char* xa = (const char*)(xg + ((size_t)tn * 64 + b_row + r) * 4096 + gc0);    \
        asm volatile("global_load_ushort %0, %1, off" : "=v"(XP_[r]) : "v"(xa));            \
        asm volatile("global_load_ushort %0, %1, off" : "=v"(XP_[4 + r]) : "v"(xa + 2048)); \
      }                                                                                     \
    }                                                                                       \
    {                                                                                       \
      bool low = (col < 8);                                                                 \
      _Pragma("unroll") for (int r = 0; r < 4; ++r) {                                       \
        float g0 = ae0[r] + ao0[r] + bfu2f((unsigned short)XU_[r]);                         \
        float g1 = ae1[r] + ao1[r] + bfu2f((unsigned short)XU_[4 + r]);                     \
        float p0 = __shfl_xor(g0, 8);                                                       \
        float p1 = __shfl_xor(g1, 8);                                                       \
        float iv = low ? g0 : p0;                                                           \
        float fv = low ? p0 : g0;                                                           \
        float gv = low ? g1 : p1;                                                           \
        float ov = low ? p1 : g1;                                                           \
        float cn = fsig(fv) * cst[r] + fsig(iv) * ftanh(gv);                                \
        cst[r] = cn;                                                                        \
        float hv = fsig(ov) * ftanh(cn);                                                    \
        if (low) tbuf[(quad * 4 + r) * 8 + (col & 7)] = f2bfu(hv);                          \
      }                                                                                     \
    }                                                                                       \
    asm volatile("s_waitcnt lgkmcnt(0)" ::: "memory");                                      \
    if (l < 16) {                                                                           \
      short8 hrow = *(const short8*)(tbuf + l * 8);                                         \
      char* dst = (char*)hseq + (size_t)t_ * 65536 + g * 1024 + (wv * 16 + l) * 16;         \
      asm volatile("global_store_dwordx4 %0, %1, off sc0 sc1" ::"v"(dst), "v"(hrow)         \
                   : "memory");                                                             \
    }                                                                                       \
    __builtin_amdgcn_s_setprio(0);                                                          \
  }

  for (int it = 0; it < 128; ++it) {
    SCAN_STEP(2 * it, xA, xB);
    SCAN_STEP(2 * it + 1, xB, xA);
  }
#undef SCAN_STEP
}

// ---------------- logits[t][b][k] = (hf|hb).w_out[k] + b_out, masked ----------------
__global__ __launch_bounds__(256) void logits_kernel(
    const unsigned short* __restrict__ hfp, const unsigned short* __restrict__ hbp,
    const unsigned short* __restrict__ wout, const float* __restrict__ bout,
    const int* __restrict__ y0, float* __restrict__ lg) {
  int t = blockIdx.x, tid = threadIdx.x;
  int b = tid >> 2, ks = tid & 3;
  int ytag = y0[(t + 1) * 64 + b];
  float mk = (ytag > 0) ? 1.f : 0.f;
  float av[6] = {0.f, 0.f, 0.f, 0.f, 0.f, 0.f};
  const char* pf = (const char*)hfp + (size_t)t * 65536;
  const char* pb = (const char*)hbp + (size_t)t * 65536;
  for (int uc = 0; uc < 64; ++uc) {
    short8 hv = *(const short8*)(pf + uc * 1024 + b * 16);
#pragma unroll
    for (int kk = 0; kk < 6; ++kk) {
      int k = ks * 6 + kk;
      short8 wv = *(const short8*)(wout + (size_t)k * 1024 + uc * 8);
#pragma unroll
      for (int j = 0; j < 8; ++j)
        av[kk] += bfu2f((unsigned short)hv[j]) * bfu2f((unsigned short)wv[j]);
    }
  }
  for (int uc = 0; uc < 64; ++uc) {
    short8 hv = *(const short8*)(pb + uc * 1024 + b * 16);
#pragma unroll
    for (int kk = 0; kk < 6; ++kk) {
      int k = ks * 6 + kk;
      short8 wv = *(const short8*)(wout + (size_t)k * 1024 + 512 + uc * 8);
#pragma unroll
      for (int j = 0; j < 8; ++j)
        av[kk] += bfu2f((unsigned short)hv[j]) * bfu2f((unsigned short)wv[j]);
    }
  }
#pragma unroll
  for (int kk = 0; kk < 6; ++kk) {
    int k = ks * 6 + kk;
    lg[((size_t)t * 64 + b) * 32 + k] = mk * (av[kk] + bout[k]);
  }
}

// ---------------- CRF forward + gold, one wave per batch ----------------
__global__ __launch_bounds__(64) void crf_kernel(
    const float* __restrict__ lg, const int* __restrict__ y0,
    const float* __restrict__ trans, float* __restrict__ res) {
  int b = blockIdx.x, l = threadIdx.x;
  __shared__ float tl[600];
  __shared__ float sc[24];
  for (int i = l; i < 576; i += 64) tl[(i / 24) * 25 + (i % 24)] = trans[i];
  if (l < 24) sc[l] = (l == 1) ? 0.f : NEGV;
  __syncthreads();
  float gold = 0.f;
  int lens = 0;
  for (int t = l; t < 256; t += 64) {
    int y1 = y0[(t + 1) * 64 + b];
    int yp = y0[t * 64 + b];
    if (y1 > 0) {
      gold += lg[((size_t)t * 64 + b) * 32 + y1] + tl[y1 * 25 + yp];
      lens += 1;
    }
  }
#pragma unroll
  for (int off = 32; off > 0; off >>= 1) {
    gold += __shfl_down(gold, off);
    lens += __shfl_down(lens, off);
  }
  gold = __shfl(gold, 0);
  lens = __shfl(lens, 0);
  int last = y0[lens * 64 + b];
  gold += tl[2 * 25 + last];
  int lc = (l < 24) ? l : 23;
  float trow[24];
#pragma unroll
  for (int j = 0; j < 24; ++j) trow[j] = tl[lc * 25 + j];
  for (int t = 0; t < 256; ++t) {
    int y1 = y0[(t + 1) * 64 + b];
    if (y1 > 0) {
      float ns = 0.f;
      if (l < 24) {
        float ht = lg[((size_t)t * 64 + b) * 32 + l];
        float mx = -3.0e38f;
        float sj[24];
#pragma unroll
        for (int j = 0; j < 24; ++j) {
          sj[j] = sc[j] + trow[j];
          mx = fmaxf(mx, sj[j]);
        }
        float sm = 0.f;
#pragma unroll
        for (int j = 0; j < 24; ++j) sm += __expf(sj[j] - mx);
        ns = ht + mx + __logf(sm);
      }
      __syncthreads();
      if (l < 24) sc[l] = ns;
      __syncthreads();
    }
  }
  float v = (l < 24) ? sc[l] + tl[2 * 25 + l] : -3.0e38f;
  float mx = v;
#pragma unroll
  for (int off = 32; off > 0; off >>= 1) mx = fmaxf(mx, __shfl_xor(mx, off));
  float se = (l < 24) ? __expf(v - mx) : 0.f;
#pragma unroll
  for (int off = 32; off > 0; off >>= 1) se += __shfl_xor(se, off);
  float Z = mx + __logf(se);
  if (l == 0) res[b] = Z - gold;
}

__global__ __launch_bounds__(64) void reduce_kernel(const float* __restrict__ res,
                                                    float* __restrict__ out) {
  int l = threadIdx.x;
  float v = res[l];
#pragma unroll
  for (int off = 32; off > 0; off >>= 1) v += __shfl_down(v, off);
  if (l == 0) out[0] = v * (1.0f / 64.0f);
}

extern "C" void kernel_launch(void* const* d_in, const int* in_sizes, int n_in,
                              void* d_out, int out_size, void* d_ws, size_t ws_size,
                              hipStream_t stream) {
  (void)in_sizes; (void)n_in; (void)out_size; (void)ws_size;
  const int* xw = (const int*)d_in[0];
  const int* y0 = (const int*)d_in[1];
  const float* emb = (const float*)d_in[2];
  const float* wihf = (const float*)d_in[3];
  const float* whhf = (const float*)d_in[4];
  const float* bfv = (const float*)d_in[5];
  const float* wihb = (const float*)d_in[6];
  const float* whhb = (const float*)d_in[7];
  const float* bbv = (const float*)d_in[8];
  const float* wo = (const float*)d_in[9];
  const float* bo = (const float*)d_in[10];
  const float* tr = (const float*)d_in[11];
  char* ws = (char*)d_ws;
  unsigned short* xg = (unsigned short*)(ws + 0);              // 134217728 B
  unsigned short* wih_c = (unsigned short*)(ws + 150994944);   // 4194304 B
  unsigned short* whh_c = (unsigned short*)(ws + 155189248);   // 4194304 B
  unsigned short* wout_c = (unsigned short*)(ws + 159383552);  // 49152 B
  float* bias_c = (float*)(ws + 159432704);                    // 16384 B
  unsigned short* hfp = (unsigned short*)(ws + 159449088);     // 16777216 B
  unsigned short* hbp = (unsigned short*)(ws + 176226304);     // 16777216 B
  float* lg = (float*)(ws + 193003520);                        // 2097152 B
  float* res = (float*)(ws + 195104768);                       // 256 B

  // pre-poison h planes to the 0xFFFF sentinel (data-is-flag protocol);
  // re-done every launch so graph replays are self-consistent.
  hipMemsetAsync(hfp, 0xFF, 16777216, stream);
  hipMemsetAsync(hbp, 0xFF, 16777216, stream);
  prep_kernel<<<16496, 256, 0, stream>>>(wihf, wihb, whhf, whhb, wo, bfv, bbv,
                                         wih_c, whh_c, wout_c, bias_c);
  gemm_xg_kernel<<<dim3(128, 32), 256, 0, stream>>>(xw, emb, wih_c, bias_c, xg);
  scan_kernel<<<512, 64, 0, stream>>>(whh_c, xg, hfp, hbp);
  logits_kernel<<<256, 256, 0, stream>>>(hfp, hbp, wout_c, bo, y0, lg);
  crf_kernel<<<64, 64, 0, stream>>>(lg, y0, tr, res);
  reduce_kernel<<<1, 64, 0, stream>>>(res, (float*)d_out);
}